// Round 11
// baseline (360.336 us; speedup 1.0000x reference)
//
#include <hip/hip_runtime.h>

// Problem constants (fixed by the reference).
#define NGRID 262144      // N = 64^3 = 2^18
#define NNZ_C 1835008     // 7 * N
#define NBKT  1024        // coarse row buckets (row >> 8)
#define TP    260         // prep LDS row stride (floats); 260*4 ≡ 0 mod 16

// Loss closed form:  loss = mean_b( Stt - 2a*C2 + a^2*C3 ),  a = Sty/C1
//   C1=<yp,yat>  C2=<yt,yat>  C3=<yat,yat>  Stt=<yt,yt>  Sty=<yt,yp>
// yat is NEVER materialized: k_gather computes each row's yat line in
// registers and folds it into C1/C2/C3 immediately.
// p2[block][160]: slot*32+b; slots 0=C1 1=C2 2=C3 3=Stt 4=Sty.

// ---------------------------------------------------------------------------
// K1: dual-family transpose (R10-green construct, minus yat zeroing).
// grid = 2048 x 256: fam 0 = yp -> yp_t, fam 1 = yt -> yt_t.
// Block 0 also zeroes the 1024-bucket histogram (R3-green idiom).
// ---------------------------------------------------------------------------
__global__ __launch_bounds__(256) void k_prep(
        const float* __restrict__ yp, const float* __restrict__ yt,
        float* __restrict__ yp_t, float* __restrict__ yt_t,
        int* __restrict__ hist) {
    __shared__ __align__(16) float T[32 * TP];
    const int tid = threadIdx.x;
    const int l = tid & 63, w = tid >> 6;
    const int fam = blockIdx.x >> 10;            // 0: yp, 1: yt
    const size_t n0 = (size_t)(blockIdx.x & 1023) * 256;
    if (blockIdx.x == 0) {
        #pragma unroll
        for (int i = 0; i < 4; ++i) hist[i * 256 + tid] = 0;
    }
    const float* src = fam ? yt : yp;
    #pragma unroll
    for (int s = 0; s < 8; ++s) {
        const int b = s * 4 + w;                 // unique (s,w) -> 0..31
        const float4 a = *(const float4*)(src + (size_t)b * NGRID + n0 + 4 * l);
        *(float4*)(&T[b * TP + 4 * l]) = a;      // ds_write_b128, row b
    }
    __syncthreads();
    float4* dst4 = (float4*)((fam ? yt_t : yp_t) + n0 * 32);
    #pragma unroll
    for (int q = 0; q < 8; ++q) {
        const int f = q * 256 + tid;             // float4 index, 0..2047
        const int n = f >> 3;                    // 0..255 local n
        const int bb = 4 * (f & 7);              // base batch of this quad
        float4 v;
        v.x = T[(bb + 0) * TP + n];
        v.y = T[(bb + 1) * TP + n];
        v.z = T[(bb + 2) * TP + n];
        v.w = T[(bb + 3) * TP + n];
        dst4[f] = v;                             // coalesced 1 KB/wave
    }
}

// ---------------------------------------------------------------------------
// K2: coarse histogram of row buckets (R3 verbatim — green).
// grid = 512 x 256, chunk = 3584.
// ---------------------------------------------------------------------------
__global__ __launch_bounds__(256) void k_hist(const int* __restrict__ rows,
                                              int* __restrict__ hist) {
    __shared__ int h[NBKT];
    const int tid = threadIdx.x;
    for (int i = tid; i < NBKT; i += 256) h[i] = 0;
    __syncthreads();
    const int chunk = NNZ_C / 512;          // 3584
    const size_t e0 = (size_t)blockIdx.x * chunk;
    for (int i = tid; i < chunk; i += 256) atomicAdd(&h[rows[e0 + i] >> 8], 1);
    __syncthreads();
    for (int i = tid; i < NBKT; i += 256)
        if (h[i]) atomicAdd(&hist[i], h[i]);
}

// ---------------------------------------------------------------------------
// K3: exclusive scan of 1024 counts -> base, cursor (R3 verbatim — green).
// ---------------------------------------------------------------------------
__global__ __launch_bounds__(1024) void k_scan(const int* __restrict__ hist,
                                               int* __restrict__ base,
                                               int* __restrict__ cursor) {
    __shared__ int s[2][NBKT];
    const int tid = threadIdx.x;
    const int v = hist[tid];
    s[0][tid] = v;
    __syncthreads();
    int p = 0;
    for (int off = 1; off < NBKT; off <<= 1) {
        int t = s[p][tid];
        if (tid >= off) t += s[p][tid - off];
        s[1 ^ p][tid] = t;
        __syncthreads();
        p ^= 1;
    }
    const int excl = s[p][tid] - v;
    base[tid] = excl;
    cursor[tid] = excl;
    if (tid == 0) base[NBKT] = NNZ_C;
}

// ---------------------------------------------------------------------------
// K4: bucket-sort edges (R3 verbatim — green). Packs (row&255)<<24 | col.
// grid = 256 x 256, chunk = 7168. Plain cached stores (no memory-side RMW).
// ---------------------------------------------------------------------------
__global__ __launch_bounds__(256) void k_reorder(
        const int* __restrict__ rows, const int* __restrict__ cols,
        const float* __restrict__ vals, int* __restrict__ cursor,
        int* __restrict__ rc_out, float* __restrict__ v_out) {
    __shared__ int h[NBKT];
    __shared__ int bl[NBKT];
    const int tid = threadIdx.x;
    for (int i = tid; i < NBKT; i += 256) h[i] = 0;
    __syncthreads();
    const int chunk = NNZ_C / 256;          // 7168
    const size_t e0 = (size_t)blockIdx.x * chunk;
    for (int i = tid; i < chunk; i += 256) atomicAdd(&h[rows[e0 + i] >> 8], 1);
    __syncthreads();
    for (int i = tid; i < NBKT; i += 256) {
        const int c = h[i];
        bl[i] = c ? atomicAdd(&cursor[i], c) : 0;
        h[i] = 0;                           // reuse as intra-block cursor
    }
    __syncthreads();
    for (int i = tid; i < chunk; i += 256) {
        const int r = rows[e0 + i];
        const int bk = r >> 8;
        const int off = atomicAdd(&h[bk], 1);
        const int pos = bl[bk] + off;
        rc_out[pos] = ((r & 255) << 24) | cols[e0 + i];
        v_out[pos] = vals[e0 + i];
    }
}

// ---------------------------------------------------------------------------
// K5: per-bucket row-sort -> CSR (NEW). grid = 1024 x 256.
// LDS 256-hist (ds atomics) -> exclusive scan (k_scan construct, 256 wide)
// -> row_ptr write (coalesced) -> scatter into final cols_s/vals_s at
// bucket-contiguous positions via LDS cursors. No global atomics.
// ---------------------------------------------------------------------------
__global__ __launch_bounds__(256) void k_reorder2(
        const int* __restrict__ rc1, const float* __restrict__ v1,
        const int* __restrict__ base, int* __restrict__ cols_s,
        float* __restrict__ vals_s, int* __restrict__ row_ptr) {
    __shared__ int s[2][256];
    __shared__ int cur[256];
    const int tid = threadIdx.x;
    const int k = blockIdx.x;
    const int start = base[k], end = base[k + 1];
    s[0][tid] = 0;
    __syncthreads();
    for (int i = start + tid; i < end; i += 256)
        atomicAdd(&s[0][((unsigned)rc1[i]) >> 24], 1);
    __syncthreads();
    const int v = s[0][tid];
    int p = 0;
    for (int off = 1; off < 256; off <<= 1) {
        int t = s[p][tid];
        if (tid >= off) t += s[p][tid - off];
        s[1 ^ p][tid] = t;
        __syncthreads();
        p ^= 1;
    }
    const int excl = s[p][tid] - v;
    row_ptr[k * 256 + tid] = start + excl;   // coalesced, 1 KB/block
    cur[tid] = excl;
    __syncthreads();
    for (int i = start + tid; i < end; i += 256) {
        const int rc = rc1[i];
        const int r8 = (int)(((unsigned)rc) >> 24);
        const int off = atomicAdd(&cur[r8], 1);
        cols_s[start + off] = rc & 0x3FFFF;
        vals_s[start + off] = v1[i];
    }
    if (k == NBKT - 1 && tid == 0) row_ptr[NGRID] = NNZ_C;
}

// ---------------------------------------------------------------------------
// K6: CSR gather + fused scalars (NEW). grid = 4096 x 256.
// Wave handles 16 rows; lanes (b=l&31, j=l>>5). Per row: acc = sum over the
// row's edges of v*yp_t[c,b] (j splits edges, shfl fold); then C1 += acc*yp,
// C2 += acc*yt, C3 += acc^2 (j==0) and Stt/Sty from the row lines (j==1).
// yat never touches memory. Per-block partials -> p2 (no atomics).
// ---------------------------------------------------------------------------
__global__ __launch_bounds__(256) void k_gather(
        const int* __restrict__ cols_s, const float* __restrict__ vals_s,
        const int* __restrict__ row_ptr, const float* __restrict__ yp_t,
        const float* __restrict__ yt_t, float* __restrict__ p2) {
    __shared__ float R[4][5][32];
    const int tid = threadIdx.x;
    const int l = tid & 63, w = tid >> 6;
    const int b = l & 31, j = l >> 5;
    float C1 = 0.f, C2 = 0.f, C3 = 0.f, TT = 0.f, SY = 0.f;
    const int r0 = blockIdx.x * 64 + w * 16;
    for (int i = 0; i < 16; ++i) {
        const int r = r0 + i;
        const int s = row_ptr[r], e = row_ptr[r + 1];
        float acc = 0.f;
        for (int idx = s + j; idx < e; idx += 2) {
            const int c = cols_s[idx];
            const float v = vals_s[idx];
            acc = fmaf(v, yp_t[(size_t)c * 32 + b], acc);
        }
        acc += __shfl_down(acc, 32);             // j==0 lanes: full row sum
        const float ypr = yp_t[(size_t)r * 32 + b];
        const float ytr = yt_t[(size_t)r * 32 + b];
        if (j == 0) {
            C1 = fmaf(acc, ypr, C1);
            C2 = fmaf(acc, ytr, C2);
            C3 = fmaf(acc, acc, C3);
        } else {
            TT = fmaf(ytr, ytr, TT);
            SY = fmaf(ytr, ypr, SY);
        }
    }
    if (j == 0) { R[w][0][b] = C1; R[w][1][b] = C2; R[w][2][b] = C3; }
    else        { R[w][3][b] = TT; R[w][4][b] = SY; }
    __syncthreads();
    if (tid < 160) {
        const int s5 = tid >> 5, bb = tid & 31;
        p2[blockIdx.x * 160 + tid] =
            R[0][s5][bb] + R[1][s5][bb] + R[2][s5][bb] + R[3][s5][bb];
    }
}

// ---------------------------------------------------------------------------
// K7a: stage-1 reduce (R8-green construct). grid = 64 x 256; 64 p2-rows each.
// ---------------------------------------------------------------------------
__global__ __launch_bounds__(256) void k_finish1(
        const float* __restrict__ p2, float* __restrict__ pr2) {
    const int tid = threadIdx.x, g = blockIdx.x;
    if (tid < 160) {
        float acc = 0.f;
        #pragma unroll
        for (int j = 0; j < 64; ++j) acc += p2[(size_t)(g * 64 + j) * 160 + tid];
        pr2[g * 160 + tid] = acc;
    }
}

// ---------------------------------------------------------------------------
// K7b: stage-2 reduce + closed-form loss (R10 verbatim — green). 1 x 256.
// ---------------------------------------------------------------------------
__global__ __launch_bounds__(256) void k_finish2(
        const float* __restrict__ pr2, float* __restrict__ out) {
    __shared__ float tot[160];
    __shared__ float lb[32];
    const int tid = threadIdx.x;
    if (tid < 160) {
        float acc = 0.f;
        #pragma unroll
        for (int j = 0; j < 64; ++j) acc += pr2[j * 160 + tid];
        tot[tid] = acc;
    }
    __syncthreads();
    if (tid < 32) {
        const float c1 = tot[0 + tid];
        const float c2 = tot[32 + tid];
        const float c3 = tot[64 + tid];
        const float stt = tot[96 + tid];
        const float sty = tot[128 + tid];
        const float a = sty / c1;
        lb[tid] = fmaf(a * a, c3, fmaf(-2.f * a, c2, stt));
    }
    __syncthreads();
    if (tid == 0) {
        float s = 0.f;
        #pragma unroll
        for (int i = 0; i < 32; ++i) s += lb[i];
        out[0] = s * (1.0f / 32.0f);
    }
}

// ===========================================================================
extern "C" void kernel_launch(void* const* d_in, const int* in_sizes, int n_in,
                              void* d_out, int out_size, void* d_ws, size_t ws_size,
                              hipStream_t stream) {
    const float* yp = (const float*)d_in[0];   // y_pred (32, N)
    const float* yt = (const float*)d_in[1];   // y_true (32, N)
    const float* Av = (const float*)d_in[2];   // A_vals (NNZ)
    const int*   Ar = (const int*)d_in[3];     // A_rows (NNZ)
    const int*   Ac = (const int*)d_in[4];     // A_cols (NNZ)
    float* out = (float*)d_out;

    // Workspace ≈ 100.2 MB (< R10's proven 102 MB footprint).
    float* ws     = (float*)d_ws;
    float* yp_t   = ws;                                   // N*32
    float* yt_t   = yp_t + (size_t)NGRID * 32;            // N*32
    int*   rc1    = (int*)(yt_t + (size_t)NGRID * 32);    // NNZ
    float* v1     = (float*)(rc1 + NNZ_C);                // NNZ
    int*   colss  = (int*)(v1 + NNZ_C);                   // NNZ
    float* valss  = (float*)(colss + NNZ_C);              // NNZ
    int*   hist   = (int*)(valss + NNZ_C);                // 1024
    int*   basep  = hist + NBKT;                          // 1025
    int*   cursor = basep + NBKT + 1;                     // 1024
    int*   rowptr = cursor + NBKT;                        // NGRID+1
    float* p2     = (float*)(rowptr + NGRID + 1);         // 4096*160
    float* pr2    = p2 + 4096 * 160;                      // 64*160

    k_prep<<<2048, 256, 0, stream>>>(yp, yt, yp_t, yt_t, hist);
    k_hist<<<512, 256, 0, stream>>>(Ar, hist);
    k_scan<<<1, 1024, 0, stream>>>(hist, basep, cursor);
    k_reorder<<<256, 256, 0, stream>>>(Ar, Ac, Av, cursor, rc1, v1);
    k_reorder2<<<NBKT, 256, 0, stream>>>(rc1, v1, basep, colss, valss, rowptr);
    k_gather<<<NGRID / 64, 256, 0, stream>>>(colss, valss, rowptr, yp_t, yt_t, p2);
    k_finish1<<<64, 256, 0, stream>>>(p2, pr2);
    k_finish2<<<1, 256, 0, stream>>>(pr2, out);
}